// Round 1
// baseline (321.015 us; speedup 1.0000x reference)
//
#include <hip/hip_runtime.h>

// Problem: 4-level mask loss.
//   per level: (sum(h_i)/(B*h*w) - union_pixels(valid boxes)/(B*h*w))^2, averaged over levels.
// Part 1 (HBM-bound): sum 22.72M floats (90.9 MB) -> ~14.5us floor at 6.3 TB/s.
// Part 2 (tiny): rasterize union of 200 boxes on 4 grids (375 rows total) via per-row bitsets.

#define NBOX_MAX 512

__device__ __forceinline__ double wave_reduce_d(double v) {
#pragma unroll
  for (int off = 32; off > 0; off >>= 1) v += __shfl_down(v, off, 64);
  return v;
}

__global__ __launch_bounds__(256) void sum_levels_kernel(
    const float4* __restrict__ p0, const float4* __restrict__ p1,
    const float4* __restrict__ p2, const float4* __restrict__ p3,
    int n0, int n1, int n2, int n3, double* __restrict__ sums) {
  const int gid = blockIdx.x * blockDim.x + threadIdx.x;
  const int stride = gridDim.x * blockDim.x;
  double a0 = 0.0, a1 = 0.0, a2 = 0.0, a3 = 0.0;
  for (int i = gid; i < n0; i += stride) {
    float4 v = p0[i];
    a0 += (double)v.x + (double)v.y + (double)v.z + (double)v.w;
  }
  for (int i = gid; i < n1; i += stride) {
    float4 v = p1[i];
    a1 += (double)v.x + (double)v.y + (double)v.z + (double)v.w;
  }
  for (int i = gid; i < n2; i += stride) {
    float4 v = p2[i];
    a2 += (double)v.x + (double)v.y + (double)v.z + (double)v.w;
  }
  for (int i = gid; i < n3; i += stride) {
    float4 v = p3[i];
    a3 += (double)v.x + (double)v.y + (double)v.z + (double)v.w;
  }
  a0 = wave_reduce_d(a0);
  a1 = wave_reduce_d(a1);
  a2 = wave_reduce_d(a2);
  a3 = wave_reduce_d(a3);
  __shared__ double sh[4][4];  // [wave][level]
  const int wid = threadIdx.x >> 6;
  if ((threadIdx.x & 63) == 0) {
    sh[wid][0] = a0; sh[wid][1] = a1; sh[wid][2] = a2; sh[wid][3] = a3;
  }
  __syncthreads();
  if (threadIdx.x == 0) {
#pragma unroll
    for (int l = 0; l < 4; l++) {
      double s = sh[0][l] + sh[1][l] + sh[2][l] + sh[3][l];
      unsafeAtomicAdd(&sums[l], s);  // hw global_atomic_add_f64; 4 per block, 4 addrs total
    }
  }
}

// Single block: rasterize box-union per level (row bitsets), then combine with sums.
__global__ __launch_bounds__(256) void finish_kernel(
    const float* __restrict__ label, int nboxes,
    const int* __restrict__ dimx_p, const int* __restrict__ dimy_p,
    const double* __restrict__ sums, float* __restrict__ out) {
  const int HH[4] = {200, 100, 50, 25};
  const int WW[4] = {334, 167, 84, 42};
  __shared__ int bx1[NBOX_MAX], bx2[NBOX_MAX], by1[NBOX_MAX], by2[NBOX_MAX];
  __shared__ int cnts[4];
  __shared__ int wred[4];
  const int tid = threadIdx.x;
  const double imx = (double)dimx_p[0];
  const double imy = (double)dimy_p[0];

#pragma unroll
  for (int lvl = 0; lvl < 4; lvl++) {
    const int h = HH[lvl], w = WW[lvl];
    // Python: sx = w / im_dimx (f64), then f32-weak multiply with f32 boxes.
    const float sx = (float)((double)w / imx);
    const float sy = (float)((double)h / imy);
    for (int j = tid; j < nboxes && j < NBOX_MAX; j += blockDim.x) {
      float b0 = label[j * 4 + 0], b1 = label[j * 4 + 1];
      float b2 = label[j * 4 + 2], b3 = label[j * 4 + 3];
      // rintf = round-half-to-even under default RNE, matches jnp.round
      int x1 = (int)fminf(fmaxf(rintf(b0 * sx), 0.0f), (float)(w - 1));
      int y1 = (int)fminf(fmaxf(rintf(b1 * sy), 0.0f), (float)(h - 1));
      int x2 = (int)fminf(fmaxf(rintf(b2 * sx), 0.0f), (float)w);
      int y2 = (int)fminf(fmaxf(rintf(b3 * sy), 0.0f), (float)h);
      bool valid = (x2 > x1) && (y2 > y1) && (x1 + x2 < w) && (y1 + y2 < h);
      bx1[j] = x1; bx2[j] = x2;
      by1[j] = valid ? y1 : 0x7fffffff;  // sentinel: invalid box never covers a row
      by2[j] = y2;
    }
    __syncthreads();
    int cnt = 0;
    if (tid < h) {  // one row per thread (h <= 200 < 256)
      unsigned words[11];  // ceil(334/32) = 11
      const int nw = (w + 31) >> 5;
      for (int k = 0; k < nw; k++) words[k] = 0u;
      for (int j = 0; j < nboxes && j < NBOX_MAX; j++) {
        if (tid < by1[j] || tid >= by2[j]) continue;
        int a = bx1[j], b = bx2[j];  // set bits [a, b)
        int k0 = a >> 5, k1 = (b - 1) >> 5;
        unsigned mfirst = 0xffffffffu << (a & 31);
        unsigned mlast = ((b & 31) == 0) ? 0xffffffffu : ((1u << (b & 31)) - 1u);
        if (k0 == k1) {
          words[k0] |= (mfirst & mlast);
        } else {
          words[k0] |= mfirst;
          for (int k = k0 + 1; k < k1; k++) words[k] = 0xffffffffu;
          words[k1] |= mlast;
        }
      }
      for (int k = 0; k < nw; k++) cnt += __popc(words[k]);
    }
    for (int off = 32; off > 0; off >>= 1) cnt += __shfl_down(cnt, off, 64);
    if ((tid & 63) == 0) wred[tid >> 6] = cnt;
    __syncthreads();
    if (tid == 0) cnts[lvl] = wred[0] + wred[1] + wred[2] + wred[3];
    __syncthreads();  // before shared arrays are reused next level
  }
  if (tid == 0) {
    double loss = 0.0;
#pragma unroll
    for (int lvl = 0; lvl < 4; lvl++) {
      double tn = 256.0 * (double)HH[lvl] * (double)WW[lvl];
      double d = (sums[lvl] - (double)cnts[lvl]) / tn;
      loss += d * d;
    }
    out[0] = (float)(loss * 0.25);
  }
}

extern "C" void kernel_launch(void* const* d_in, const int* in_sizes, int n_in,
                              void* d_out, int out_size, void* d_ws, size_t ws_size,
                              hipStream_t stream) {
  const float4* p0 = (const float4*)d_in[0];
  const float4* p1 = (const float4*)d_in[1];
  const float4* p2 = (const float4*)d_in[2];
  const float4* p3 = (const float4*)d_in[3];
  const float* label = (const float*)d_in[4];
  const int* dimx = (const int*)d_in[5];
  const int* dimy = (const int*)d_in[6];
  float* out = (float*)d_out;
  double* sums = (double*)d_ws;

  const int n0 = in_sizes[0] / 4;  // all level sizes divisible by 4
  const int n1 = in_sizes[1] / 4;
  const int n2 = in_sizes[2] / 4;
  const int n3 = in_sizes[3] / 4;
  const int nboxes = in_sizes[4] / 4;

  hipMemsetAsync(d_ws, 0, 4 * sizeof(double), stream);

  const int threads = 256;
  const int blocks = 2048;  // 8 blocks/CU, grid-stride; level0 ~8 float4/thread
  sum_levels_kernel<<<blocks, threads, 0, stream>>>(p0, p1, p2, p3, n0, n1, n2, n3, sums);
  finish_kernel<<<1, threads, 0, stream>>>(label, nboxes, dimx, dimy, sums, out);
}

// Round 2
// 133.109 us; speedup vs baseline: 2.4117x; 2.4117x over previous
//
#include <hip/hip_runtime.h>

// 4-level mask loss. Part 1: sum 22.72M floats (90.9 MB) -> HBM-bound, ~15us floor.
// Part 2: union-rasterize 200 boxes over 4 grids as (level,row,word32) tasks.
//
// R1 lessons: (a) NO same-address atomics for the reduction (8192 f64 atomics on one
// cache line serialized to ~120us) -> per-block partials in d_ws instead.
// (b) NO dynamically-indexed private arrays (words[11] went to scratch, 117us
// single-block kernel) -> one register mask per (row,word) task.

__device__ __forceinline__ double wave_red_d(double v) {
#pragma unroll
  for (int off = 32; off > 0; off >>= 1) v += __shfl_down(v, off, 64);
  return v;
}
__device__ __forceinline__ int wave_red_i(int v) {
#pragma unroll
  for (int off = 32; off > 0; off >>= 1) v += __shfl_down(v, off, 64);
  return v;
}

#define SUM_BLOCKS 1024
#define RAST_BLOCKS 12
// d_ws layout: [0, 32KB): double partials[SUM_BLOCKS][4]
//              [32768, +192): int counts[RAST_BLOCKS][4]
#define COUNTS_OFF 32768

__global__ __launch_bounds__(256) void sum_levels_kernel(
    const float4* __restrict__ p0, const float4* __restrict__ p1,
    const float4* __restrict__ p2, const float4* __restrict__ p3,
    int n0, int n1, int n2, int n3, double* __restrict__ partials) {
  const int gid = blockIdx.x * blockDim.x + threadIdx.x;
  const int stride = gridDim.x * blockDim.x;
  double a0 = 0.0, a1 = 0.0, a2 = 0.0, a3 = 0.0;
  for (int i = gid; i < n0; i += stride) {
    float4 v = p0[i];
    a0 += (double)((v.x + v.y) + (v.z + v.w));
  }
  for (int i = gid; i < n1; i += stride) {
    float4 v = p1[i];
    a1 += (double)((v.x + v.y) + (v.z + v.w));
  }
  for (int i = gid; i < n2; i += stride) {
    float4 v = p2[i];
    a2 += (double)((v.x + v.y) + (v.z + v.w));
  }
  for (int i = gid; i < n3; i += stride) {
    float4 v = p3[i];
    a3 += (double)((v.x + v.y) + (v.z + v.w));
  }
  a0 = wave_red_d(a0); a1 = wave_red_d(a1); a2 = wave_red_d(a2); a3 = wave_red_d(a3);
  __shared__ double sh[4][4];  // [wave][level]
  const int wid = threadIdx.x >> 6;
  if ((threadIdx.x & 63) == 0) {
    sh[wid][0] = a0; sh[wid][1] = a1; sh[wid][2] = a2; sh[wid][3] = a3;
  }
  __syncthreads();
  if (threadIdx.x == 0) {
    double* dst = &partials[blockIdx.x * 4];
#pragma unroll
    for (int l = 0; l < 4; l++) dst[l] = sh[0][l] + sh[1][l] + sh[2][l] + sh[3][l];
  }
}

// Tasks: level 0: 200 rows x 11 words = 2200; level 1: 100x6=600; level 2: 50x3=150;
// level 3: 25x2=50. Total 3000. Each thread owns one word -> one register mask.
__global__ __launch_bounds__(256) void raster_kernel(
    const float* __restrict__ label, int nboxes,
    const int* __restrict__ dimx_p, const int* __restrict__ dimy_p,
    int* __restrict__ counts) {
  __shared__ int sx1[4][256], sx2[4][256], sy1[4][256], sy2[4][256];
  const int tid = threadIdx.x;
  const double imx = (double)dimx_p[0];
  const double imy = (double)dimy_p[0];
  const int nb = nboxes < 256 ? nboxes : 256;

  // Precompute clipped box coords per (level, box): 4*nb pairs across 256 threads.
  for (int idx = tid; idx < 4 * nb; idx += 256) {
    const int lvl = idx / nb;
    const int j = idx - lvl * nb;
    const int w = (lvl == 0) ? 334 : (lvl == 1) ? 167 : (lvl == 2) ? 84 : 42;
    const int h = (lvl == 0) ? 200 : (lvl == 1) ? 100 : (lvl == 2) ? 50 : 25;
    const float sx = (float)((double)w / imx);  // matches jnp f64-div -> f32 weak mul
    const float sy = (float)((double)h / imy);
    float b0 = label[j * 4 + 0], b1 = label[j * 4 + 1];
    float b2 = label[j * 4 + 2], b3 = label[j * 4 + 3];
    int x1 = (int)fminf(fmaxf(rintf(b0 * sx), 0.0f), (float)(w - 1));
    int y1 = (int)fminf(fmaxf(rintf(b1 * sy), 0.0f), (float)(h - 1));
    int x2 = (int)fminf(fmaxf(rintf(b2 * sx), 0.0f), (float)w);
    int y2 = (int)fminf(fmaxf(rintf(b3 * sy), 0.0f), (float)h);
    bool valid = (x2 > x1) && (y2 > y1) && (x1 + x2 < w) && (y1 + y2 < h);
    sx1[lvl][j] = x1; sx2[lvl][j] = x2;
    sy1[lvl][j] = valid ? y1 : 0x7fffffff;  // sentinel: never covers any row
    sy2[lvl][j] = y2;
  }
  __syncthreads();

  int c0 = 0, c1 = 0, c2 = 0, c3 = 0;
  for (int t = blockIdx.x * 256 + tid; t < 3000; t += gridDim.x * 256) {
    int lvl, r, wd;
    if (t < 2200)      { lvl = 0; unsigned u = t;        r = u / 11; wd = u - r * 11; }
    else if (t < 2800) { lvl = 1; unsigned u = t - 2200; r = u / 6;  wd = u - r * 6; }
    else if (t < 2950) { lvl = 2; unsigned u = t - 2800; r = u / 3;  wd = u - r * 3; }
    else               { lvl = 3; unsigned u = t - 2950; r = u >> 1; wd = u & 1; }
    const int col0 = wd << 5;
    unsigned m = 0;
    for (int j = 0; j < nb; j++) {
      const int y1 = sy1[lvl][j], y2 = sy2[lvl][j];
      const int a = sx1[lvl][j], b = sx2[lvl][j];
      const bool inrow = (r >= y1) & (r < y2);
      int lo = a - col0; lo = lo > 0 ? lo : 0;
      int hi = b - col0; hi = hi < 32 ? hi : 32;
      if (inrow && hi > lo) {
        unsigned mh = (hi >= 32) ? 0xffffffffu : ((1u << (hi & 31)) - 1u);
        m |= mh & (0xffffffffu << (lo & 31));
      }
    }
    const int pc = __popc(m);
    if (lvl == 0) c0 += pc; else if (lvl == 1) c1 += pc;
    else if (lvl == 2) c2 += pc; else c3 += pc;
  }
  c0 = wave_red_i(c0); c1 = wave_red_i(c1); c2 = wave_red_i(c2); c3 = wave_red_i(c3);
  __shared__ int shc[4][4];
  const int wid = tid >> 6;
  if ((tid & 63) == 0) { shc[wid][0] = c0; shc[wid][1] = c1; shc[wid][2] = c2; shc[wid][3] = c3; }
  __syncthreads();
  if (tid == 0) {
    int* dst = &counts[blockIdx.x * 4];
#pragma unroll
    for (int l = 0; l < 4; l++) dst[l] = shc[0][l] + shc[1][l] + shc[2][l] + shc[3][l];
  }
}

__global__ __launch_bounds__(256) void finish_kernel(
    const double* __restrict__ partials, const int* __restrict__ counts,
    float* __restrict__ out) {
  const int tid = threadIdx.x;
  double s0 = 0.0, s1 = 0.0, s2 = 0.0, s3 = 0.0;
  for (int b = tid; b < SUM_BLOCKS; b += 256) {
    s0 += partials[b * 4 + 0]; s1 += partials[b * 4 + 1];
    s2 += partials[b * 4 + 2]; s3 += partials[b * 4 + 3];
  }
  int c0 = 0, c1 = 0, c2 = 0, c3 = 0;
  if (tid < RAST_BLOCKS) {
    c0 = counts[tid * 4 + 0]; c1 = counts[tid * 4 + 1];
    c2 = counts[tid * 4 + 2]; c3 = counts[tid * 4 + 3];
  }
  s0 = wave_red_d(s0); s1 = wave_red_d(s1); s2 = wave_red_d(s2); s3 = wave_red_d(s3);
  c0 = wave_red_i(c0); c1 = wave_red_i(c1); c2 = wave_red_i(c2); c3 = wave_red_i(c3);
  __shared__ double shd[4][4];
  __shared__ int shi[4][4];
  const int wid = tid >> 6;
  if ((tid & 63) == 0) {
    shd[wid][0] = s0; shd[wid][1] = s1; shd[wid][2] = s2; shd[wid][3] = s3;
    shi[wid][0] = c0; shi[wid][1] = c1; shi[wid][2] = c2; shi[wid][3] = c3;
  }
  __syncthreads();
  if (tid == 0) {
    const double HH[4] = {200.0, 100.0, 50.0, 25.0};
    const double WW[4] = {334.0, 167.0, 84.0, 42.0};
    double loss = 0.0;
#pragma unroll
    for (int l = 0; l < 4; l++) {
      double s = shd[0][l] + shd[1][l] + shd[2][l] + shd[3][l];
      double c = (double)(shi[0][l] + shi[1][l] + shi[2][l] + shi[3][l]);
      double tn = 256.0 * HH[l] * WW[l];
      double d = (s - c) / tn;
      loss += d * d;
    }
    out[0] = (float)(loss * 0.25);
  }
}

extern "C" void kernel_launch(void* const* d_in, const int* in_sizes, int n_in,
                              void* d_out, int out_size, void* d_ws, size_t ws_size,
                              hipStream_t stream) {
  const float4* p0 = (const float4*)d_in[0];
  const float4* p1 = (const float4*)d_in[1];
  const float4* p2 = (const float4*)d_in[2];
  const float4* p3 = (const float4*)d_in[3];
  const float* label = (const float*)d_in[4];
  const int* dimx = (const int*)d_in[5];
  const int* dimy = (const int*)d_in[6];
  float* out = (float*)d_out;
  double* partials = (double*)d_ws;
  int* counts = (int*)((char*)d_ws + COUNTS_OFF);

  const int n0 = in_sizes[0] / 4;
  const int n1 = in_sizes[1] / 4;
  const int n2 = in_sizes[2] / 4;
  const int n3 = in_sizes[3] / 4;
  const int nboxes = in_sizes[4] / 4;

  sum_levels_kernel<<<SUM_BLOCKS, 256, 0, stream>>>(p0, p1, p2, p3, n0, n1, n2, n3, partials);
  raster_kernel<<<RAST_BLOCKS, 256, 0, stream>>>(label, nboxes, dimx, dimy, counts);
  finish_kernel<<<1, 256, 0, stream>>>(partials, counts, out);
}